// Round 7
// baseline (479.103 us; speedup 1.0000x reference)
//
#include <hip/hip_runtime.h>
#include <math.h>

#define B_   128
#define N1_  128
#define N2_  384
#define N_   512
#define E_   1024
#define DIN  64
#define DFC  128

// workspace layout (floats)
#define ACC_TOP  0
#define ACC_BOT  128
#define POOL_OFF 256                          // B*64 = 8192
#define RNI_OFF  (POOL_OFF + B_*DIN)          // 8448:  B*N1 reciprocal rownorms
#define CNI_OFF  (RNI_OFF + B_*N1_)           // 24832: B*N2 reciprocal colnorms
#define BI_OFF   (CNI_OFF + B_*N2_)           // 73984: B*N1 argmax ints
#define EB_OFF   (BI_OFF + B_*N1_)            // 90368: B*384*128 exp-matrix transposed (25 MB)
#define ZERO_CNT (POOL_OFF + B_*DIN)

// ---------------- init ----------------
// grid 33, block 256
__global__ void k_init(float* ws, float* out) {
    int idx = blockIdx.x * 256 + threadIdx.x;
    if (idx < ZERO_CNT) ws[idx] = 0.f;
    if (blockIdx.x == 0 && threadIdx.x < 4) out[128 + threadIdx.x] = 0.f;
}

// ---------------- front: pool (y<8) | rownorm+argmax (8<=y<40) | colnorm (40<=y<46) ----------------
// grid (B, 46), block 256
__global__ void k_front(const float* __restrict__ c_hs, const float* __restrict__ c_valid,
                        const float* __restrict__ att, float* __restrict__ ws) {
    __shared__ float4 sred4[256];
    float* sred = (float*)sred4;
    int b = blockIdx.x, y = blockIdx.y, t = threadIdx.x;
    if (y < 8) {
        // masked mean-pool partial: 64 rows
        int chunk = y * 64;
        int d4 = t & 15, rl = t >> 4;
        const float4* X4 = (const float4*)(c_hs + (size_t)b * N_ * DIN);
        const float* V = c_valid + (size_t)b * N_;
        float4 acc = {0.f, 0.f, 0.f, 0.f};
        #pragma unroll
        for (int r = chunk + rl; r < chunk + 64; r += 16) {
            float4 x = X4[r * 16 + d4];
            float v = V[r];
            acc.x += x.x * v; acc.y += x.y * v; acc.z += x.z * v; acc.w += x.w * v;
        }
        sred4[t] = acc; __syncthreads();
        for (int off = 128; off >= 16; off >>= 1) {
            if (t < off) {
                float4 o = sred4[t + off];
                sred4[t].x += o.x; sred4[t].y += o.y; sred4[t].z += o.z; sred4[t].w += o.w;
            }
            __syncthreads();
        }
        if (t < 16) {
            float4 s = sred4[t];
            float* p = ws + POOL_OFF + b * DIN + t * 4;
            atomicAdd(&p[0], s.x); atomicAdd(&p[1], s.y);
            atomicAdd(&p[2], s.z); atomicAdd(&p[3], s.w);
        }
    } else if (y < 40) {
        // reciprocal rownorm + argmax: one wave per row
        int wv = t >> 6, ln = t & 63;
        int r = (y - 8) * 4 + wv;
        const float* row = att + ((size_t)b * N1_ + r) * N2_;
        float ssq = 0.f, best = -1e30f; int bidx = 0;
        #pragma unroll
        for (int q = 0; q < 6; ++q) {
            float v = row[ln + 64 * q];
            ssq += v * v;
            if (v > best) { best = v; bidx = ln + 64 * q; }   // ascending: > keeps first
        }
        for (int off = 32; off > 0; off >>= 1) {
            ssq += __shfl_xor(ssq, off, 64);
            float ov = __shfl_xor(best, off, 64);
            int oi = __shfl_xor(bidx, off, 64);
            if (ov > best || (ov == best && oi < bidx)) { best = ov; bidx = oi; }
        }
        if (ln == 0) {
            ws[RNI_OFF + b * N1_ + r] = 1.f / fmaxf(sqrtf(ssq), 1e-12f);
            ((int*)ws)[BI_OFF + b * N1_ + r] = bidx;
        }
    } else {
        // reciprocal colnorm: 64 cols, 4 row-quarters
        int c = (y - 40) * 64 + (t & 63);
        int q = t >> 6;
        const float* A = att + (size_t)b * N1_ * N2_;
        float s = 0.f;
        #pragma unroll 8
        for (int j = q * 32; j < q * 32 + 32; ++j) { float v = A[j * N2_ + c]; s += v * v; }
        sred[t] = s; __syncthreads();
        if (t < 64)
            ws[CNI_OFF + b * N2_ + (y - 40) * 64 + t] =
                1.f / fmaxf(sqrtf(sred[t] + sred[t + 64] + sred[t + 128] + sred[t + 192]), 1e-12f);
    }
}

// ---------------- prep: eB[r][j] = exp(-att[j,r]*rinv[j]) (transposed) ----------------
// grid (12, B), block 256. Strip of 32 att-cols.
#define TP 129
__global__ void k_prep(const float* __restrict__ att, float* __restrict__ ws) {
    __shared__ float tile[32 * TP];
    __shared__ float rinv[N1_];
    int b = blockIdx.y, t = threadIdx.x;
    int r0 = blockIdx.x * 32;
    if (t < N1_) rinv[t] = ws[RNI_OFF + b * N1_ + t];
    __syncthreads();
    const float4* att4 = (const float4*)(att + (size_t)b * N1_ * N2_);
    int c8 = t & 7, jb = t >> 3;
    #pragma unroll
    for (int p = 0; p < 4; ++p) {
        int j = jb + p * 32;
        float4 a = att4[j * 96 + blockIdx.x * 8 + c8];
        float rv = rinv[j];
        tile[(c8 * 4 + 0) * TP + j] = a.x * rv;
        tile[(c8 * 4 + 1) * TP + j] = a.y * rv;
        tile[(c8 * 4 + 2) * TP + j] = a.z * rv;
        tile[(c8 * 4 + 3) * TP + j] = a.w * rv;
    }
    __syncthreads();
    int j4 = t & 31, cb = t >> 5;
    float4* eb4 = (float4*)(ws + EB_OFF + ((size_t)b * N2_ + r0) * N1_);
    #pragma unroll
    for (int p = 0; p < 4; ++p) {
        int c = cb + p * 8;
        float4 e;
        e.x = __expf(-tile[c * TP + j4 * 4]);
        e.y = __expf(-tile[c * TP + j4 * 4 + 1]);
        e.z = __expf(-tile[c * TP + j4 * 4 + 2]);
        e.w = __expf(-tile[c * TP + j4 * 4 + 3]);
        eb4[c * 32 + j4] = e;
    }
}

// ---------------- mask scan v4: fill-shaped. 2 rows/block, 1 float4-col/thread ----------------
// grid (256, B), block 256 (4 waves)
__global__ void k_scan(const float* __restrict__ att, const float* __restrict__ mapping,
                       const float* __restrict__ samelb, float* __restrict__ ws) {
    __shared__ float rt[4], rb[4];
    int b = blockIdx.y, t = threadIdx.x;
    int i = 2 * blockIdx.x + (t >> 7);           // global row 0..511
    int c4 = t & 127;                            // float4 column 0..127
    const float4* m4 = (const float4*)(mapping + ((size_t)b * N_ + i) * N_);
    const float4* s4 = (const float4*)(samelb + ((size_t)b * N_ + i) * N_);
    float4 m = m4[c4];
    float4 s = s4[c4];
    float4 w = {1.f, 1.f, 1.f, 1.f};
    if (i < N1_) {
        if (c4 >= 32) {                          // cols >=128: w = exp(-att*cninv)
            int a4i = c4 - 32;                   // attention float4 col 0..95
            float4 a = ((const float4*)(att + ((size_t)b * N1_ + i) * N2_))[a4i];
            float4 cn = ((const float4*)(ws + CNI_OFF + b * N2_))[a4i];
            w.x = __expf(-a.x * cn.x);
            w.y = __expf(-a.y * cn.y);
            w.z = __expf(-a.z * cn.z);
            w.w = __expf(-a.w * cn.w);
        }
    } else {
        if (c4 < 32) {                           // cols <128: w = eB[r][j]
            w = ((const float4*)(ws + EB_OFF + ((size_t)b * N2_ + (i - N1_)) * N1_))[c4];
        }
    }
    float top = m.x * w.x + m.y * w.y + m.z * w.z + m.w * w.w;
    float bot = s.x * w.x + s.y * w.y + s.z * w.z + s.w * w.w;
    for (int off = 32; off > 0; off >>= 1) {
        top += __shfl_down(top, off, 64);
        bot += __shfl_down(bot, off, 64);
    }
    int wv = t >> 6, ln = t & 63;
    if (ln == 0) { rt[wv] = top; rb[wv] = bot; }
    __syncthreads();
    if (t == 0) {
        atomicAdd(&ws[ACC_TOP + b], rt[0] + rt[1] + rt[2] + rt[3]);
        atomicAdd(&ws[ACC_BOT + b], rb[0] + rb[1] + rb[2] + rb[3]);
    }
}

// ---------------- back: kabsch+pair+finalize (y==0) | scores MLP (y==1) ----------------
__device__ inline float bred(float* s2, float v, int t) {
    for (int off = 32; off > 0; off >>= 1) v += __shfl_down(v, off, 64);
    if ((t & 63) == 0) s2[t >> 6] = v;
    __syncthreads();
    float r = s2[0] + s2[1];
    __syncthreads();
    return r;
}

// grid (B, 2), block 128
__global__ void k_back(const float* __restrict__ coords, const float* __restrict__ upd,
                       const float* __restrict__ nm, const int* __restrict__ ei,
                       const float* __restrict__ W0, const float* __restrict__ b0,
                       const float* __restrict__ W1, const float* __restrict__ b1,
                       const float* __restrict__ W2, const float* __restrict__ b2,
                       const float* __restrict__ W3, const float* __restrict__ b3,
                       const float* __restrict__ ws, float* __restrict__ out) {
    __shared__ float sh[2 * DFC];
    int b = blockIdx.x, t = threadIdx.x;
    if (blockIdx.y == 1) {
        // ---- scores MLP ----
        float* pool = sh;           // 64
        float* h    = sh + 64;      // 128
        __shared__ float part[DFC];
        if (t < DIN) pool[t] = ws[POOL_OFF + b * DIN + t] * (1.0f / 128.0f);
        __syncthreads();
        float a = b0[t];
        #pragma unroll
        for (int i = 0; i < DIN; ++i) a += pool[i] * W0[i * DFC + t];
        float hv = fmaxf(a, 0.f);
        __syncthreads(); h[t] = hv; __syncthreads();
        a = b1[t];
        #pragma unroll
        for (int i = 0; i < DFC; ++i) a += h[i] * W1[i * DFC + t];
        hv = fmaxf(a, 0.f);
        __syncthreads(); h[t] = hv; __syncthreads();
        a = b2[t];
        #pragma unroll
        for (int i = 0; i < DFC; ++i) a += h[i] * W2[i * DFC + t];
        part[t] = fmaxf(a, 0.f) * W3[t];
        __syncthreads();
        for (int off = 64; off > 0; off >>= 1) { if (t < off) part[t] += part[t + off]; __syncthreads(); }
        if (t == 0) out[b] = 1.f / (1.f + expf(-(part[0] + b3[0])));
        return;
    }
    // ---- Kabsch ----
    float* s2 = sh;
    __shared__ float Rsh[9], Tsh[3];
    int bidx = ((const int*)ws)[BI_OFF + b * N1_ + t];
    float P[3], Q[3];
    const float* up = upd + ((size_t)b * N_ + t) * 3;
    P[0] = up[0]; P[1] = up[1]; P[2] = up[2];
    const float* qp = coords + ((size_t)b * N_ + N1_ + bidx) * 3;
    Q[0] = qp[0]; Q[1] = qp[1]; Q[2] = qp[2];
    float Pm[3], Qm[3];
    for (int a = 0; a < 3; ++a) Pm[a] = bred(s2, P[a], t) * (1.f / 128.f);
    for (int a = 0; a < 3; ++a) Qm[a] = bred(s2, Q[a], t) * (1.f / 128.f);
    float H[9];
    for (int a = 0; a < 3; ++a)
        for (int c = 0; c < 3; ++c)
            H[a * 3 + c] = bred(s2, (P[a] - Pm[a]) * (Q[c] - Qm[c]), t) * (1.f / 8.f);
    if (t == 0) {
        double Hd[3][3];
        for (int a = 0; a < 3; ++a) for (int c = 0; c < 3; ++c) Hd[a][c] = (double)H[a * 3 + c];
        double A[3][3], V[3][3] = {{1,0,0},{0,1,0},{0,0,1}};
        for (int i = 0; i < 3; ++i)
            for (int j = 0; j < 3; ++j) {
                double z = 0; for (int c = 0; c < 3; ++c) z += Hd[c][i] * Hd[c][j];
                A[i][j] = z;
            }
        for (int sweep = 0; sweep < 8; ++sweep) {
            const int PQ[3][2] = {{0,1},{0,2},{1,2}};
            for (int r = 0; r < 3; ++r) {
                int p = PQ[r][0], q = PQ[r][1];
                double apq = A[p][q];
                if (fabs(apq) < 1e-300) continue;
                double tau = (A[q][q] - A[p][p]) / (2.0 * apq);
                double tt = (tau >= 0 ? 1.0 : -1.0) / (fabs(tau) + sqrt(1.0 + tau * tau));
                double c = 1.0 / sqrt(1.0 + tt * tt), s = tt * c;
                for (int k = 0; k < 3; ++k) { double akp = A[k][p], akq = A[k][q]; A[k][p] = c * akp - s * akq; A[k][q] = s * akp + c * akq; }
                for (int k = 0; k < 3; ++k) { double apk = A[p][k], aqk = A[q][k]; A[p][k] = c * apk - s * aqk; A[q][k] = s * apk + c * aqk; }
                for (int k = 0; k < 3; ++k) { double vkp = V[k][p], vkq = V[k][q]; V[k][p] = c * vkp - s * vkq; V[k][q] = s * vkp + c * vkq; }
            }
        }
        double lam[3] = {A[0][0], A[1][1], A[2][2]};
        int id[3] = {0, 1, 2};
        if (lam[id[0]] < lam[id[1]]) { int x = id[0]; id[0] = id[1]; id[1] = x; }
        if (lam[id[0]] < lam[id[2]]) { int x = id[0]; id[0] = id[2]; id[2] = x; }
        if (lam[id[1]] < lam[id[2]]) { int x = id[1]; id[1] = id[2]; id[2] = x; }
        double u[3][3], v[3][3], sv[3];
        for (int i = 0; i < 3; ++i) {
            for (int k = 0; k < 3; ++k) v[i][k] = V[k][id[i]];
            double uv[3];
            for (int c = 0; c < 3; ++c) uv[c] = Hd[c][0] * v[i][0] + Hd[c][1] * v[i][1] + Hd[c][2] * v[i][2];
            double n = sqrt(uv[0] * uv[0] + uv[1] * uv[1] + uv[2] * uv[2]);
            sv[i] = n;
            if (n > 1e-150) { u[i][0] = uv[0] / n; u[i][1] = uv[1] / n; u[i][2] = uv[2] / n; }
            else { u[i][0] = u[i][1] = u[i][2] = 0.0; }
        }
        if (sv[2] < 1e-12 * fmax(sv[0], 1e-300)) {
            u[2][0] = u[0][1] * u[1][2] - u[0][2] * u[1][1];
            u[2][1] = u[0][2] * u[1][0] - u[0][0] * u[1][2];
            u[2][2] = u[0][0] * u[1][1] - u[0][1] * u[1][0];
        }
        double det = Hd[0][0] * (Hd[1][1] * Hd[2][2] - Hd[1][2] * Hd[2][1])
                   - Hd[0][1] * (Hd[1][0] * Hd[2][2] - Hd[1][2] * Hd[2][0])
                   + Hd[0][2] * (Hd[1][0] * Hd[2][1] - Hd[1][1] * Hd[2][0]);
        double dsg = (det > 0.0) ? 1.0 : ((det < 0.0) ? -1.0 : 0.0);
        for (int a = 0; a < 3; ++a)
            for (int c = 0; c < 3; ++c)
                Rsh[a * 3 + c] = (float)(u[0][a] * v[0][c] + u[1][a] * v[1][c] + dsg * u[2][a] * v[2][c]);
        for (int a = 0; a < 3; ++a)
            Tsh[a] = Qm[a] - (Rsh[a * 3] * Pm[0] + Rsh[a * 3 + 1] * Pm[1] + Rsh[a * 3 + 2] * Pm[2]);
    }
    __syncthreads();
    float Pp[3];
    for (int a = 0; a < 3; ++a)
        Pp[a] = Rsh[a * 3] * P[0] + Rsh[a * 3 + 1] * P[1] + Rsh[a * 3 + 2] * P[2] + Tsh[a];
    float mk = (nm[b * N1_ + t] > 0.5f) ? 1.f : 0.f;
    float dx = Pp[0] - Q[0], dy = Pp[1] - Q[1], dz = Pp[2] - Q[2];
    float rsum = bred(s2, mk * (dx * dx + dy * dy + dz * dz), t);
    float msum = bred(s2, mk, t);
    float Ppm[3];
    for (int a = 0; a < 3; ++a) Ppm[a] = bred(s2, Pp[a], t) * (1.f / 128.f);
    if (t == 0) {
        float cnt = fmaxf(msum * 3.f, 1.f);
        atomicAdd(&out[129], (rsum / cnt) * (1.f / 128.f));
        float cen = 0.f;
        for (int a = 0; a < 3; ++a) { float d2 = Ppm[a] - Qm[a]; cen += d2 * d2; }
        atomicAdd(&out[131], (cen / 3.f) * (1.f / 128.f));
    }
    // ---- fused pairdst ----
    const float* C = coords + (size_t)b * N_ * 3;
    const float* U = upd + (size_t)b * N_ * 3;
    const int* e = ei + (size_t)b * E_ * 2;
    float acc = 0.f;
    for (int idx = t; idx < E_; idx += 128) {
        int a0 = e[idx * 2], a1 = e[idx * 2 + 1];
        float ex = C[a0 * 3] - C[a1 * 3], ey = C[a0 * 3 + 1] - C[a1 * 3 + 1], ez = C[a0 * 3 + 2] - C[a1 * 3 + 2];
        float d0 = sqrtf(ex * ex + ey * ey + ez * ez + 1e-12f);
        ex = U[a0 * 3] - U[a1 * 3]; ey = U[a0 * 3 + 1] - U[a1 * 3 + 1]; ez = U[a0 * 3 + 2] - U[a1 * 3 + 2];
        float d1 = sqrtf(ex * ex + ey * ey + ez * ez + 1e-12f);
        acc += d1 - d0;
    }
    float psum = bred(s2, acc, t);
    if (t == 0) atomicAdd(&out[130], fabsf(psum) * (1.f / 128.f));
    // ---- attn_loss finalize ----
    if (b == 0) {
        float top = ws[ACC_TOP + t], bot = ws[ACC_BOT + t];
        float v = top / (bot - top + 1.0f);
        float s = bred(s2, v, t);
        if (t == 0) out[128] = s * (1.0f / 128.0f);
    }
}

extern "C" void kernel_launch(void* const* d_in, const int* in_sizes, int n_in,
                              void* d_out, int out_size, void* d_ws, size_t ws_size,
                              hipStream_t stream) {
    const float* c_hs      = (const float*)d_in[0];
    const float* attention = (const float*)d_in[1];
    const float* coords    = (const float*)d_in[2];
    const float* upd       = (const float*)d_in[3];
    const float* c_valid   = (const float*)d_in[4];
    const float* nm        = (const float*)d_in[5];
    const float* mapping   = (const float*)d_in[6];
    const float* samelb    = (const float*)d_in[7];
    const int*   ei        = (const int*)d_in[8];
    const float* W0 = (const float*)d_in[9],  *b0 = (const float*)d_in[10];
    const float* W1 = (const float*)d_in[11], *b1 = (const float*)d_in[12];
    const float* W2 = (const float*)d_in[13], *b2 = (const float*)d_in[14];
    const float* W3 = (const float*)d_in[15], *b3 = (const float*)d_in[16];
    float* out = (float*)d_out;
    float* ws  = (float*)d_ws;

    hipLaunchKernelGGL(k_init,  dim3(33),       dim3(256), 0, stream, ws, out);
    hipLaunchKernelGGL(k_front, dim3(B_, 46),   dim3(256), 0, stream, c_hs, c_valid, attention, ws);
    hipLaunchKernelGGL(k_prep,  dim3(12, B_),   dim3(256), 0, stream, attention, ws);
    hipLaunchKernelGGL(k_scan,  dim3(256, B_),  dim3(256), 0, stream, attention, mapping, samelb, ws);
    hipLaunchKernelGGL(k_back,  dim3(B_, 2),    dim3(128), 0, stream, coords, upd, nm, ei,
                       W0, b0, W1, b1, W2, b2, W3, b3, ws, out);
}

// Round 8
// 387.457 us; speedup vs baseline: 1.2365x; 1.2365x over previous
//
#include <hip/hip_runtime.h>
#include <math.h>

#define B_   128
#define N1_  128
#define N2_  384
#define N_   512
#define E_   1024
#define DIN  64
#define DFC  128

// workspace layout (floats)
#define ACC_TOP  0
#define ACC_BOT  128
#define POOL_OFF 256                          // B*64 = 8192
#define RNI_OFF  (POOL_OFF + B_*DIN)          // 8448:  B*N1 reciprocal rownorms
#define BI_OFF   (RNI_OFF + B_*N1_)           // 24832: B*N1 argmax ints
#define CNI_OFF  (BI_OFF + B_*N1_)            // 41216: B*N2 col ssq -> reciprocal colnorms (in-place)

// ---------------- init ----------------
// grid 192, block 256  (zero acc+pool 8448 and col-ssq 49152)
__global__ void k_init(float* ws, float* out) {
    int idx = blockIdx.x * 256 + threadIdx.x;
    if (idx < 256 + B_ * DIN) ws[idx] = 0.f;
    if (idx < B_ * N2_) ws[CNI_OFF + idx] = 0.f;
    if (idx < 4) out[128 + idx] = 0.f;
}

// ---------------- front: pool (y<8) | att single pass: rownorm+argmax+col-ssq (y in 8..39) ----
// grid (B, 40), block 256
__global__ void k_front(const float* __restrict__ c_hs, const float* __restrict__ c_valid,
                        const float* __restrict__ att, float* __restrict__ ws) {
    __shared__ float4 sred4[256];
    int b = blockIdx.x, y = blockIdx.y, t = threadIdx.x;
    if (y < 8) {
        // masked mean-pool partial: 64 rows
        int chunk = y * 64;
        int d4 = t & 15, rl = t >> 4;
        const float4* X4 = (const float4*)(c_hs + (size_t)b * N_ * DIN);
        const float* V = c_valid + (size_t)b * N_;
        float4 acc = {0.f, 0.f, 0.f, 0.f};
        #pragma unroll
        for (int r = chunk + rl; r < chunk + 64; r += 16) {
            float4 x = X4[r * 16 + d4];
            float v = V[r];
            acc.x += x.x * v; acc.y += x.y * v; acc.z += x.z * v; acc.w += x.w * v;
        }
        sred4[t] = acc; __syncthreads();
        for (int off = 128; off >= 16; off >>= 1) {
            if (t < off) {
                float4 o = sred4[t + off];
                sred4[t].x += o.x; sred4[t].y += o.y; sred4[t].z += o.z; sred4[t].w += o.w;
            }
            __syncthreads();
        }
        if (t < 16) {
            float4 s = sred4[t];
            float* p = ws + POOL_OFF + b * DIN + t * 4;
            atomicAdd(&p[0], s.x); atomicAdd(&p[1], s.y);
            atomicAdd(&p[2], s.z); atomicAdd(&p[3], s.w);
        }
        return;
    }
    // att pass: 4 rows (one per wave), fused row-ssq + argmax + col-ssq partials
    float* colacc = (float*)sred4;               // 384 floats
    for (int c = t; c < N2_; c += 256) colacc[c] = 0.f;
    __syncthreads();
    int wv = t >> 6, ln = t & 63;
    int r = (y - 8) * 4 + wv;
    const float* row = att + ((size_t)b * N1_ + r) * N2_;
    float vv[6];
    float ssq = 0.f, best = -1e30f; int bidx = 0;
    #pragma unroll
    for (int q = 0; q < 6; ++q) {
        float v = row[ln + 64 * q];
        vv[q] = v;
        ssq += v * v;
        if (v > best) { best = v; bidx = ln + 64 * q; }   // ascending: > keeps first
    }
    #pragma unroll
    for (int q = 0; q < 6; ++q) atomicAdd(&colacc[ln + 64 * q], vv[q] * vv[q]);
    for (int off = 32; off > 0; off >>= 1) {
        ssq += __shfl_xor(ssq, off, 64);
        float ov = __shfl_xor(best, off, 64);
        int oi = __shfl_xor(bidx, off, 64);
        if (ov > best || (ov == best && oi < bidx)) { best = ov; bidx = oi; }
    }
    if (ln == 0) {
        ws[RNI_OFF + b * N1_ + r] = 1.f / fmaxf(sqrtf(ssq), 1e-12f);
        ((int*)ws)[BI_OFF + b * N1_ + r] = bidx;
    }
    __syncthreads();
    for (int c = t; c < N2_; c += 256)
        atomicAdd(&ws[CNI_OFF + b * N2_ + c], colacc[c]);
}

// ---------------- fin: col ssq -> reciprocal norm (in place) ----------------
// grid (B), block 384
__global__ void k_fin(float* __restrict__ ws) {
    int b = blockIdx.x, t = threadIdx.x;
    float v = ws[CNI_OFF + b * N2_ + t];
    ws[CNI_OFF + b * N2_ + t] = 1.f / fmaxf(sqrtf(v), 1e-12f);
}

// ---------------- fused mask scan: 16 rows/block; B-blocks transpose att in LDS ----------------
// grid (32, B), block 256
#define EWS 132
__global__ void k_scan(const float* __restrict__ att, const float* __restrict__ mapping,
                       const float* __restrict__ samelb, float* __restrict__ ws) {
    __shared__ float cninv[N2_];
    __shared__ float rinv[N1_];
    __shared__ float ew[16 * EWS];
    __shared__ float rt[4], rb[4];
    int b = blockIdx.y, t = threadIdx.x;
    float top = 0.f, bot = 0.f;
    if (blockIdx.x < 8) {
        // type A: rows [0,128). cols<128: count; cols>=128: exp(-att*cninv) inline
        int i0 = blockIdx.x * 16;
        for (int j = t; j < N2_; j += 256) cninv[j] = ws[CNI_OFF + b * N2_ + j];
        __syncthreads();
        const float4* m4 = (const float4*)(mapping + ((size_t)b * N_ + i0) * N_);
        const float4* s4 = (const float4*)(samelb + ((size_t)b * N_ + i0) * N_);
        const float4* a4 = (const float4*)(att + ((size_t)b * N1_ + i0) * N2_);
        float4 md[2], sd[2], av[6], mv[6], sv[6];
        int ri[6], ci[6];
        #pragma unroll
        for (int k = 0; k < 2; ++k) { int g = t + k * 256; md[k] = m4[(g >> 5) * 128 + (g & 31)]; }
        #pragma unroll
        for (int k = 0; k < 2; ++k) { int g = t + k * 256; sd[k] = s4[(g >> 5) * 128 + (g & 31)]; }
        #pragma unroll
        for (int k = 0; k < 6; ++k) {
            int g = t + k * 256; ri[k] = g / 96; ci[k] = g - ri[k] * 96;
            av[k] = a4[ri[k] * 96 + ci[k]];
        }
        #pragma unroll
        for (int k = 0; k < 6; ++k) mv[k] = m4[ri[k] * 128 + 32 + ci[k]];
        #pragma unroll
        for (int k = 0; k < 6; ++k) sv[k] = s4[ri[k] * 128 + 32 + ci[k]];
        #pragma unroll
        for (int k = 0; k < 2; ++k) {
            top += md[k].x + md[k].y + md[k].z + md[k].w;
            bot += sd[k].x + sd[k].y + sd[k].z + sd[k].w;
        }
        #pragma unroll
        for (int k = 0; k < 6; ++k) {
            int cb = ci[k] * 4;
            float e0 = __expf(-av[k].x * cninv[cb]);
            float e1 = __expf(-av[k].y * cninv[cb + 1]);
            float e2 = __expf(-av[k].z * cninv[cb + 2]);
            float e3 = __expf(-av[k].w * cninv[cb + 3]);
            top += mv[k].x * e0 + mv[k].y * e1 + mv[k].z * e2 + mv[k].w * e3;
            bot += sv[k].x * e0 + sv[k].y * e1 + sv[k].z * e2 + sv[k].w * e3;
        }
    } else {
        // type B: rows [128,512) in 16-row tiles; ew[r][j] = exp(-att[j,c0+r]*rinv[j]) built in LDS
        int tb = blockIdx.x - 8;                  // 0..23
        int c0 = tb * 16;
        int i0 = N1_ + c0;
        if (t < N1_) rinv[t] = ws[RNI_OFF + b * N1_ + t];
        __syncthreads();
        const float4* att4 = (const float4*)(att + (size_t)b * N1_ * N2_);
        int c4q = t & 3, jb = t >> 2;             // 64 j per pass
        #pragma unroll
        for (int p = 0; p < 2; ++p) {
            int j = jb + p * 64;
            float4 a = att4[j * 96 + tb * 4 + c4q];
            float rv = rinv[j];
            ew[(c4q * 4 + 0) * EWS + j] = __expf(-a.x * rv);
            ew[(c4q * 4 + 1) * EWS + j] = __expf(-a.y * rv);
            ew[(c4q * 4 + 2) * EWS + j] = __expf(-a.z * rv);
            ew[(c4q * 4 + 3) * EWS + j] = __expf(-a.w * rv);
        }
        __syncthreads();
        const float4* m4 = (const float4*)(mapping + ((size_t)b * N_ + i0) * N_);
        const float4* s4 = (const float4*)(samelb + ((size_t)b * N_ + i0) * N_);
        float4 mv[2], sv[2], mc[6], sc[6];
        #pragma unroll
        for (int k = 0; k < 2; ++k) { int g = t + k * 256; mv[k] = m4[(g >> 5) * 128 + (g & 31)]; }
        #pragma unroll
        for (int k = 0; k < 2; ++k) { int g = t + k * 256; sv[k] = s4[(g >> 5) * 128 + (g & 31)]; }
        #pragma unroll
        for (int k = 0; k < 6; ++k) {
            int g = t + k * 256; int r = g / 96, c = g - r * 96;
            mc[k] = m4[r * 128 + 32 + c];
        }
        #pragma unroll
        for (int k = 0; k < 6; ++k) {
            int g = t + k * 256; int r = g / 96, c = g - r * 96;
            sc[k] = s4[r * 128 + 32 + c];
        }
        #pragma unroll
        for (int k = 0; k < 2; ++k) {
            int g = t + k * 256; int r = g >> 5, c4 = g & 31;
            float4 w = *(const float4*)&ew[r * EWS + c4 * 4];
            top += mv[k].x * w.x + mv[k].y * w.y + mv[k].z * w.z + mv[k].w * w.w;
            bot += sv[k].x * w.x + sv[k].y * w.y + sv[k].z * w.z + sv[k].w * w.w;
        }
        #pragma unroll
        for (int k = 0; k < 6; ++k) {
            top += mc[k].x + mc[k].y + mc[k].z + mc[k].w;
            bot += sc[k].x + sc[k].y + sc[k].z + sc[k].w;
        }
    }
    for (int off = 32; off > 0; off >>= 1) {
        top += __shfl_down(top, off, 64);
        bot += __shfl_down(bot, off, 64);
    }
    int wv = t >> 6, ln = t & 63;
    if (ln == 0) { rt[wv] = top; rb[wv] = bot; }
    __syncthreads();
    if (t == 0) {
        atomicAdd(&ws[ACC_TOP + b], rt[0] + rt[1] + rt[2] + rt[3]);
        atomicAdd(&ws[ACC_BOT + b], rb[0] + rb[1] + rb[2] + rb[3]);
    }
}

// ---------------- back: kabsch+pair+finalize (y==0) | scores MLP (y==1) ----------------
__device__ inline float bred(float* s2, float v, int t) {
    for (int off = 32; off > 0; off >>= 1) v += __shfl_down(v, off, 64);
    if ((t & 63) == 0) s2[t >> 6] = v;
    __syncthreads();
    float r = s2[0] + s2[1];
    __syncthreads();
    return r;
}

// grid (B, 2), block 128
__global__ void k_back(const float* __restrict__ coords, const float* __restrict__ upd,
                       const float* __restrict__ nm, const int* __restrict__ ei,
                       const float* __restrict__ W0, const float* __restrict__ b0,
                       const float* __restrict__ W1, const float* __restrict__ b1,
                       const float* __restrict__ W2, const float* __restrict__ b2,
                       const float* __restrict__ W3, const float* __restrict__ b3,
                       const float* __restrict__ ws, float* __restrict__ out) {
    __shared__ float sh[2 * DFC];
    int b = blockIdx.x, t = threadIdx.x;
    if (blockIdx.y == 1) {
        // ---- scores MLP ----
        float* pool = sh;           // 64
        float* h    = sh + 64;      // 128
        __shared__ float part[DFC];
        if (t < DIN) pool[t] = ws[POOL_OFF + b * DIN + t] * (1.0f / 128.0f);
        __syncthreads();
        float a = b0[t];
        #pragma unroll
        for (int i = 0; i < DIN; ++i) a += pool[i] * W0[i * DFC + t];
        float hv = fmaxf(a, 0.f);
        __syncthreads(); h[t] = hv; __syncthreads();
        a = b1[t];
        #pragma unroll
        for (int i = 0; i < DFC; ++i) a += h[i] * W1[i * DFC + t];
        hv = fmaxf(a, 0.f);
        __syncthreads(); h[t] = hv; __syncthreads();
        a = b2[t];
        #pragma unroll
        for (int i = 0; i < DFC; ++i) a += h[i] * W2[i * DFC + t];
        part[t] = fmaxf(a, 0.f) * W3[t];
        __syncthreads();
        for (int off = 64; off > 0; off >>= 1) { if (t < off) part[t] += part[t + off]; __syncthreads(); }
        if (t == 0) out[b] = 1.f / (1.f + expf(-(part[0] + b3[0])));
        return;
    }
    // ---- Kabsch ----
    float* s2 = sh;
    __shared__ float Rsh[9], Tsh[3];
    int bidx = ((const int*)ws)[BI_OFF + b * N1_ + t];
    float P[3], Q[3];
    const float* up = upd + ((size_t)b * N_ + t) * 3;
    P[0] = up[0]; P[1] = up[1]; P[2] = up[2];
    const float* qp = coords + ((size_t)b * N_ + N1_ + bidx) * 3;
    Q[0] = qp[0]; Q[1] = qp[1]; Q[2] = qp[2];
    float Pm[3], Qm[3];
    for (int a = 0; a < 3; ++a) Pm[a] = bred(s2, P[a], t) * (1.f / 128.f);
    for (int a = 0; a < 3; ++a) Qm[a] = bred(s2, Q[a], t) * (1.f / 128.f);
    float H[9];
    for (int a = 0; a < 3; ++a)
        for (int c = 0; c < 3; ++c)
            H[a * 3 + c] = bred(s2, (P[a] - Pm[a]) * (Q[c] - Qm[c]), t) * (1.f / 8.f);
    if (t == 0) {
        double Hd[3][3];
        for (int a = 0; a < 3; ++a) for (int c = 0; c < 3; ++c) Hd[a][c] = (double)H[a * 3 + c];
        double A[3][3], V[3][3] = {{1,0,0},{0,1,0},{0,0,1}};
        for (int i = 0; i < 3; ++i)
            for (int j = 0; j < 3; ++j) {
                double z = 0; for (int c = 0; c < 3; ++c) z += Hd[c][i] * Hd[c][j];
                A[i][j] = z;
            }
        for (int sweep = 0; sweep < 8; ++sweep) {
            const int PQ[3][2] = {{0,1},{0,2},{1,2}};
            for (int r = 0; r < 3; ++r) {
                int p = PQ[r][0], q = PQ[r][1];
                double apq = A[p][q];
                if (fabs(apq) < 1e-300) continue;
                double tau = (A[q][q] - A[p][p]) / (2.0 * apq);
                double tt = (tau >= 0 ? 1.0 : -1.0) / (fabs(tau) + sqrt(1.0 + tau * tau));
                double c = 1.0 / sqrt(1.0 + tt * tt), s = tt * c;
                for (int k = 0; k < 3; ++k) { double akp = A[k][p], akq = A[k][q]; A[k][p] = c * akp - s * akq; A[k][q] = s * akp + c * akq; }
                for (int k = 0; k < 3; ++k) { double apk = A[p][k], aqk = A[q][k]; A[p][k] = c * apk - s * aqk; A[q][k] = s * apk + c * aqk; }
                for (int k = 0; k < 3; ++k) { double vkp = V[k][p], vkq = V[k][q]; V[k][p] = c * vkp - s * vkq; V[k][q] = s * vkp + c * vkq; }
            }
        }
        double lam[3] = {A[0][0], A[1][1], A[2][2]};
        int id[3] = {0, 1, 2};
        if (lam[id[0]] < lam[id[1]]) { int x = id[0]; id[0] = id[1]; id[1] = x; }
        if (lam[id[0]] < lam[id[2]]) { int x = id[0]; id[0] = id[2]; id[2] = x; }
        if (lam[id[1]] < lam[id[2]]) { int x = id[1]; id[1] = id[2]; id[2] = x; }
        double u[3][3], v[3][3], sv[3];
        for (int i = 0; i < 3; ++i) {
            for (int k = 0; k < 3; ++k) v[i][k] = V[k][id[i]];
            double uv[3];
            for (int c = 0; c < 3; ++c) uv[c] = Hd[c][0] * v[i][0] + Hd[c][1] * v[i][1] + Hd[c][2] * v[i][2];
            double n = sqrt(uv[0] * uv[0] + uv[1] * uv[1] + uv[2] * uv[2]);
            sv[i] = n;
            if (n > 1e-150) { u[i][0] = uv[0] / n; u[i][1] = uv[1] / n; u[i][2] = uv[2] / n; }
            else { u[i][0] = u[i][1] = u[i][2] = 0.0; }
        }
        if (sv[2] < 1e-12 * fmax(sv[0], 1e-300)) {
            u[2][0] = u[0][1] * u[1][2] - u[0][2] * u[1][1];
            u[2][1] = u[0][2] * u[1][0] - u[0][0] * u[1][2];
            u[2][2] = u[0][0] * u[1][1] - u[0][1] * u[1][0];
        }
        double det = Hd[0][0] * (Hd[1][1] * Hd[2][2] - Hd[1][2] * Hd[2][1])
                   - Hd[0][1] * (Hd[1][0] * Hd[2][2] - Hd[1][2] * Hd[2][0])
                   + Hd[0][2] * (Hd[1][0] * Hd[2][1] - Hd[1][1] * Hd[2][0]);
        double dsg = (det > 0.0) ? 1.0 : ((det < 0.0) ? -1.0 : 0.0);
        for (int a = 0; a < 3; ++a)
            for (int c = 0; c < 3; ++c)
                Rsh[a * 3 + c] = (float)(u[0][a] * v[0][c] + u[1][a] * v[1][c] + dsg * u[2][a] * v[2][c]);
        for (int a = 0; a < 3; ++a)
            Tsh[a] = Qm[a] - (Rsh[a * 3] * Pm[0] + Rsh[a * 3 + 1] * Pm[1] + Rsh[a * 3 + 2] * Pm[2]);
    }
    __syncthreads();
    float Pp[3];
    for (int a = 0; a < 3; ++a)
        Pp[a] = Rsh[a * 3] * P[0] + Rsh[a * 3 + 1] * P[1] + Rsh[a * 3 + 2] * P[2] + Tsh[a];
    float mk = (nm[b * N1_ + t] > 0.5f) ? 1.f : 0.f;
    float dx = Pp[0] - Q[0], dy = Pp[1] - Q[1], dz = Pp[2] - Q[2];
    float rsum = bred(s2, mk * (dx * dx + dy * dy + dz * dz), t);
    float msum = bred(s2, mk, t);
    float Ppm[3];
    for (int a = 0; a < 3; ++a) Ppm[a] = bred(s2, Pp[a], t) * (1.f / 128.f);
    if (t == 0) {
        float cnt = fmaxf(msum * 3.f, 1.f);
        atomicAdd(&out[129], (rsum / cnt) * (1.f / 128.f));
        float cen = 0.f;
        for (int a = 0; a < 3; ++a) { float d2 = Ppm[a] - Qm[a]; cen += d2 * d2; }
        atomicAdd(&out[131], (cen / 3.f) * (1.f / 128.f));
    }
    // ---- fused pairdst ----
    const float* C = coords + (size_t)b * N_ * 3;
    const float* U = upd + (size_t)b * N_ * 3;
    const int* e = ei + (size_t)b * E_ * 2;
    float acc = 0.f;
    for (int idx = t; idx < E_; idx += 128) {
        int a0 = e[idx * 2], a1 = e[idx * 2 + 1];
        float ex = C[a0 * 3] - C[a1 * 3], ey = C[a0 * 3 + 1] - C[a1 * 3 + 1], ez = C[a0 * 3 + 2] - C[a1 * 3 + 2];
        float d0 = sqrtf(ex * ex + ey * ey + ez * ez + 1e-12f);
        ex = U[a0 * 3] - U[a1 * 3]; ey = U[a0 * 3 + 1] - U[a1 * 3 + 1]; ez = U[a0 * 3 + 2] - U[a1 * 3 + 2];
        float d1 = sqrtf(ex * ex + ey * ey + ez * ez + 1e-12f);
        acc += d1 - d0;
    }
    float psum = bred(s2, acc, t);
    if (t == 0) atomicAdd(&out[130], fabsf(psum) * (1.f / 128.f));
    // ---- attn_loss finalize ----
    if (b == 0) {
        float top = ws[ACC_TOP + t], bot = ws[ACC_BOT + t];
        float v = top / (bot - top + 1.0f);
        float s = bred(s2, v, t);
        if (t == 0) out[128] = s * (1.0f / 128.0f);
    }
}

extern "C" void kernel_launch(void* const* d_in, const int* in_sizes, int n_in,
                              void* d_out, int out_size, void* d_ws, size_t ws_size,
                              hipStream_t stream) {
    const float* c_hs      = (const float*)d_in[0];
    const float* attention = (const float*)d_in[1];
    const float* coords    = (const float*)d_in[2];
    const float* upd       = (const float*)d_in[3];
    const float* c_valid   = (const float*)d_in[4];
    const float* nm        = (const float*)d_in[5];
    const float* mapping   = (const float*)d_in[6];
    const float* samelb    = (const float*)d_in[7];
    const int*   ei        = (const int*)d_in[8];
    const float* W0 = (const float*)d_in[9],  *b0 = (const float*)d_in[10];
    const float* W1 = (const float*)d_in[11], *b1 = (const float*)d_in[12];
    const float* W2 = (const float*)d_in[13], *b2 = (const float*)d_in[14];
    const float* W3 = (const float*)d_in[15], *b3 = (const float*)d_in[16];
    float* out = (float*)d_out;
    float* ws  = (float*)d_ws;

    hipLaunchKernelGGL(k_init,  dim3(192),     dim3(256), 0, stream, ws, out);
    hipLaunchKernelGGL(k_front, dim3(B_, 40),  dim3(256), 0, stream, c_hs, c_valid, attention, ws);
    hipLaunchKernelGGL(k_fin,   dim3(B_),      dim3(N2_), 0, stream, ws);
    hipLaunchKernelGGL(k_scan,  dim3(32, B_),  dim3(256), 0, stream, attention, mapping, samelb, ws);
    hipLaunchKernelGGL(k_back,  dim3(B_, 2),   dim3(128), 0, stream, coords, upd, nm, ei,
                       W0, b0, W1, b1, W2, b2, W3, b3, ws, out);
}